// Round 10
// baseline (271.108 us; speedup 1.0000x reference)
//
#include <hip/hip_runtime.h>
#include <hip/hip_bf16.h>

// MHA block: out = softmax(mask(Q Wq^T (K Wk^T)^T / 8)) (V Wv^T) Wo^T
// B=2, L=2048, D=1024, H=16, Dk=64.
// R10 = R9 GEMMs verbatim; attn: in-block K-split. 512 thr = 2 groups x 4 waves.
// Group g handles keys [g*1024, (g+1)*1024), Q-tile 128 rows (32/wave).
// Fixed-shift softmax (m=8) makes partials associative: combine = add O, add lsum.
// Grid (32 bh, 16 qt) = 512 blocks = 2/CU -> 4 waves/SIMD.

using bf8   = __attribute__((ext_vector_type(8))) short;    // 8 bf16
using f4    = __attribute__((ext_vector_type(4))) float;
using f16v  = __attribute__((ext_vector_type(16))) float;
using u32x4 = __attribute__((ext_vector_type(4))) unsigned int;

__device__ __forceinline__ short f2bf(float f) {
  unsigned u = __float_as_uint(f);
  u = (u + 0x7FFFu + ((u >> 16) & 1u)) >> 16;   // RNE
  return (short)(unsigned short)u;
}

__device__ __forceinline__ unsigned cvt_pk_bf16(float lo, float hi) {
  unsigned r;
  asm("v_cvt_pk_bf16_f32 %0, %1, %2" : "=v"(r) : "v"(lo), "v"(hi));
  return r;
}

// with a=b=x: a' = low-half bcast, b' = high-half bcast
__device__ __forceinline__ void permswap(unsigned &a, unsigned &b) {
  asm volatile("v_permlane32_swap_b32 %0, %1" : "+v"(a), "+v"(b));
}

// ======== GEMM body (R9 verbatim, green): 128x128 tile, BK=32, double-buffered ========
template<bool FP32IN, bool HEADOUT>
__device__ __forceinline__ void gemm_body(const void* __restrict__ Ain,
                                          const float* __restrict__ W,
                                          void* __restrict__ Out,
                                          int bm, int bn, float scale)
{
  constexpr int LDT = 40;                      // 80B rows, 16B aligned
  __shared__ short As[2][128 * LDT];
  __shared__ short Ws[2][128 * LDT];

  const int tid  = threadIdx.x;
  const int lane = tid & 63;
  const int wv   = tid >> 6;
  const int wm = wv >> 1, wn = wv & 1;         // wave tile 64x64
  const int l15 = lane & 15;
  const int lk8 = (lane >> 4) * 8;

  const f4 fz = {0.f, 0.f, 0.f, 0.f};
  f4 acc[4][4];
  #pragma unroll
  for (int mi = 0; mi < 4; ++mi)
    #pragma unroll
    for (int ni = 0; ni < 4; ++ni) acc[mi][ni] = fz;

  const int arow = tid >> 1;                   // 0..127
  const int acol = (tid & 1) * 16;             // 0 / 16

  float4 ra[4]; float4 rw[4]; bf8 ar[2];

  auto loadA = [&](int kt) {
    if constexpr (FP32IN) {
      const float4* src = (const float4*)((const float*)Ain + (long)(bm + arow) * 1024 + kt + acol);
      #pragma unroll
      for (int j = 0; j < 4; ++j) ra[j] = src[j];
    } else {
      const short* src = (const short*)Ain + (long)(bm + arow) * 1024 + kt + acol;
      ar[0] = *(const bf8*)src;
      ar[1] = *(const bf8*)(src + 8);
    }
  };
  auto loadW = [&](int kt) {
    const float4* src = (const float4*)(W + (long)(bn + arow) * 1024 + kt + acol);
    #pragma unroll
    for (int j = 0; j < 4; ++j) rw[j] = src[j];
  };
  auto writeTile = [&](int buf) {
    short* ap = &As[buf][arow * LDT + acol];
    if constexpr (FP32IN) {
      #pragma unroll
      for (int half = 0; half < 2; ++half) {
        u32x4 pk;
        pk[0] = cvt_pk_bf16(ra[2*half].x,   ra[2*half].y);
        pk[1] = cvt_pk_bf16(ra[2*half].z,   ra[2*half].w);
        pk[2] = cvt_pk_bf16(ra[2*half+1].x, ra[2*half+1].y);
        pk[3] = cvt_pk_bf16(ra[2*half+1].z, ra[2*half+1].w);
        *(bf8*)(ap + 8*half) = __builtin_bit_cast(bf8, pk);
      }
    } else {
      *(bf8*)ap     = ar[0];
      *(bf8*)(ap+8) = ar[1];
    }
    short* wp = &Ws[buf][arow * LDT + acol];
    #pragma unroll
    for (int half = 0; half < 2; ++half) {
      u32x4 pk;
      pk[0] = cvt_pk_bf16(rw[2*half].x,   rw[2*half].y);
      pk[1] = cvt_pk_bf16(rw[2*half].z,   rw[2*half].w);
      pk[2] = cvt_pk_bf16(rw[2*half+1].x, rw[2*half+1].y);
      pk[3] = cvt_pk_bf16(rw[2*half+1].z, rw[2*half+1].w);
      *(bf8*)(wp + 8*half) = __builtin_bit_cast(bf8, pk);
    }
  };

  loadA(0); loadW(0); writeTile(0);
  __syncthreads();

  for (int ktI = 0; ktI < 32; ++ktI) {
    const int cur = ktI & 1;
    if (ktI < 31) { loadA((ktI + 1) * 32); loadW((ktI + 1) * 32); }

    bf8 af[4], bfr[4];
    #pragma unroll
    for (int mi = 0; mi < 4; ++mi)
      af[mi] = *(const bf8*)&As[cur][(wm*64 + mi*16 + l15) * LDT + lk8];
    #pragma unroll
    for (int ni = 0; ni < 4; ++ni)
      bfr[ni] = *(const bf8*)&Ws[cur][(wn*64 + ni*16 + l15) * LDT + lk8];
    #pragma unroll
    for (int mi = 0; mi < 4; ++mi)
      #pragma unroll
      for (int ni = 0; ni < 4; ++ni)
        acc[mi][ni] = __builtin_amdgcn_mfma_f32_16x16x32_bf16(af[mi], bfr[ni], acc[mi][ni], 0, 0, 0);

    if (ktI < 31) writeTile(cur ^ 1);
    __syncthreads();
  }

  #pragma unroll
  for (int mi = 0; mi < 4; ++mi) {
    #pragma unroll
    for (int ni = 0; ni < 4; ++ni) {
      #pragma unroll
      for (int r = 0; r < 4; ++r) {
        int mg = bm + wm*64 + mi*16 + (lane >> 4)*4 + r;
        int ng = bn + wn*64 + ni*16 + l15;
        float val = acc[mi][ni][r] * scale;
        if constexpr (HEADOUT) {
          int b = mg >> 11, l = mg & 2047;
          int h = ng >> 6,  d = ng & 63;
          ((short*)Out)[(((long)(b*16 + h) * 2048 + l) << 6) + d] = f2bf(val);
        } else {
          ((float*)Out)[(long)mg * 1024 + ng] = val;
        }
      }
    }
  }
}

// merged Q/K/V projection: blockIdx.z selects stream -> 768 blocks
__global__ __launch_bounds__(256)
void qkv_gemm(const float* __restrict__ q, const float* __restrict__ k,
              const float* __restrict__ v, const float* __restrict__ wq,
              const float* __restrict__ wk, const float* __restrict__ wv,
              short* __restrict__ qh, short* __restrict__ kh, short* __restrict__ vh)
{
  const int z = blockIdx.z;
  const float* A = (z == 0) ? q : (z == 1) ? k : v;
  const float* W = (z == 0) ? wq : (z == 1) ? wk : wv;
  short* Out     = (z == 0) ? qh : (z == 1) ? kh : vh;
  const float scale = (z == 0) ? 0.125f : 1.0f;
  gemm_body<true, true>(A, W, Out, blockIdx.x * 128, blockIdx.y * 128, scale);
}

__global__ __launch_bounds__(256)
void out_gemm(const short* __restrict__ att, const float* __restrict__ wo,
              float* __restrict__ out)
{
  gemm_body<false, false>(att, wo, out, blockIdx.x * 128, blockIdx.y * 128, 1.0f);
}

// ======== flash attention with in-block K-split ========
// LDS pool: KVb[0..3] = K tiles (grp*2+buf), KVb[4..7] = V tiles (4 + grp*2+buf).
// Each tile 64 keys x 64 dk bf16, 128B rows, XOR-swizzled (R3-green formulas).
// Exchange buffer (epilogue) reuses KVb[0..5] as float[4][64][48].
__global__ __launch_bounds__(512, 4)
void attn_fwd(const short* __restrict__ qh, const short* __restrict__ kh,
              const short* __restrict__ vh, const int* __restrict__ mask,
              short* __restrict__ att)
{
  __shared__ short KVb[8][4096];               // 64 KB
  __shared__ short biasB[2][2][64];            // [grp][buf][key]

  const int t = threadIdx.x, lane = t & 63, w = t >> 6;
  const int l31 = lane & 31, hi = lane >> 5;
  const unsigned swz = (unsigned)((l31 & 7) << 4);
  const int grp = w >> 2;                      // key-half this wave computes
  const int bh = blockIdx.x, b = bh >> 4, h = bh & 15;
  const int qrow0 = blockIdx.y * 128 + (w & 3) * 32;
  const long base = (long)bh * 2048 * 64;

  // Q B-frags: lane holds col q=l31, k-slice hi*8 of each 16-dk step
  bf8 qb[4];
  {
    const short* qp = qh + base + (long)(qrow0 + l31) * 64 + hi * 8;
    #pragma unroll
    for (int s = 0; s < 4; ++s) qb[s] = *(const bf8*)(qp + s * 16);
  }
  bf8 qb4;                                   // bias k-step: B[k=0][q] = 1
  #pragma unroll
  for (int i = 0; i < 8; ++i) qb4[i] = 0;
  qb4[0] = hi ? (short)0 : (short)0x3F80;
  bf8 ones;                                  // lsum column: B[k][n=0] = 1
  #pragma unroll
  for (int i = 0; i < 8; ++i) ones[i] = (l31 == 0) ? (short)0x3F80 : (short)0;

  f16v o0, o1, o2, fz16;
  #pragma unroll
  for (int i = 0; i < 16; ++i) { o0[i] = 0.f; o1[i] = 0.f; o2[i] = 0.f; fz16[i] = 0.f; }

  // staging (ALL 512 threads stage BOTH groups, R3-green pattern per group):
  // thread covers K/V row sr, 8-short chunk at c8, for group g at key base g*1024.
  const int sr = t & 63, c8 = (t >> 6) << 3;   // t>>6 in 0..7
  const short* kgp0 = kh + base + c8;
  const short* vgp0 = vh + base + c8;
  const short* kgp1 = kh + base + (long)1024 * 64 + c8;
  const short* vgp1 = vh + base + (long)1024 * 64 + c8;
  const unsigned kwb = (unsigned)(sr * 128 + c8 * 2) ^ ((unsigned)(sr & 7) << 4);

  // prologue: stage tile 0 of both groups -> buf 0
  {
    bf8 k0 = *(const bf8*)(kgp0 + (long)sr * 64);
    bf8 k1 = *(const bf8*)(kgp1 + (long)sr * 64);
    bf8 v0 = *(const bf8*)(vgp0 + (long)sr * 64);
    bf8 v1 = *(const bf8*)(vgp1 + (long)sr * 64);
    *(bf8*)((char*)KVb[0] + kwb) = k0;         // K grp0 buf0
    *(bf8*)((char*)KVb[2] + kwb) = k1;         // K grp1 buf0
    #pragma unroll
    for (int i = 0; i < 8; ++i) {
      unsigned a = (unsigned)((c8 + i) * 128 + sr * 2) ^ ((unsigned)i << 4);
      *(short*)((char*)KVb[4] + a) = v0[i];    // V grp0 buf0
      *(short*)((char*)KVb[6] + a) = v1[i];    // V grp1 buf0
    }
    if (t < 64) {
      biasB[0][0][t] = mask[b * 2048 + t]        ? (short)0 : (short)0xC680;
      biasB[1][0][t] = mask[b * 2048 + 1024 + t] ? (short)0 : (short)0xC680;
    }
  }
  __syncthreads();

  for (int it = 0; it < 16; ++it) {
    const int cur = it & 1;
    bf8 k0, k1, v0, v1; int mv0 = 1, mv1 = 1;
    if (it < 15) {                           // issue next-tile loads early (T14)
      const int kt = (it + 1) * 64;
      k0 = *(const bf8*)(kgp0 + (long)(kt + sr) * 64);
      k1 = *(const bf8*)(kgp1 + (long)(kt + sr) * 64);
      v0 = *(const bf8*)(vgp0 + (long)(kt + sr) * 64);
      v1 = *(const bf8*)(vgp1 + (long)(kt + sr) * 64);
      if (t < 64) {
        mv0 = mask[b * 2048 + kt + t];
        mv1 = mask[b * 2048 + 1024 + kt + t];
      }
    }

    const char* Kc = (const char*)KVb[grp * 2 + cur];
    const char* Vc = (const char*)KVb[4 + grp * 2 + cur];

    // ---- S^T = mfma(K, Q) + bias column (R3-green body) ----
    f16v sT[2];
    #pragma unroll
    for (int kb2 = 0; kb2 < 2; ++kb2) {
      bf8 ba;
      #pragma unroll
      for (int i = 0; i < 8; ++i) ba[i] = 0;
      ba[0] = hi ? (short)0 : biasB[grp][cur][kb2 * 32 + l31];
      sT[kb2] = __builtin_amdgcn_mfma_f32_32x32x16_bf16(ba, qb4, fz16, 0, 0, 0);
      #pragma unroll
      for (int s = 0; s < 4; ++s) {
        unsigned ab = (unsigned)((kb2 * 32 + l31) * 128 + s * 32 + hi * 16) ^ swz;
        bf8 ka = *(const bf8*)(Kc + ab);
        sT[kb2] = __builtin_amdgcn_mfma_f32_32x32x16_bf16(ka, qb[s], sT[kb2], 0, 0, 0);
      }
    }

    // ---- p = exp2(s*log2e - 8*log2e); pack bf16 pairs; swap halves ----
    unsigned Lh[16], Hh[16];
    #pragma unroll
    for (int t2 = 0; t2 < 2; ++t2)
      #pragma unroll
      for (int pi = 0; pi < 8; ++pi) {
        float pe0 = exp2f(sT[t2][2*pi]   * 1.44269504f - 11.5415603f);
        float pe1 = exp2f(sT[t2][2*pi+1] * 1.44269504f - 11.5415603f);
        unsigned pkv = cvt_pk_bf16(pe0, pe1);
        unsigned Lv = pkv, Hv = pkv;
        permswap(Lv, Hv);
        Lh[t2*8 + pi] = Lv; Hh[t2*8 + pi] = Hv;
      }

    // ---- O += P V ; lsum += P 1 ----
    #pragma unroll
    for (int t2 = 0; t2 < 2; ++t2)
      #pragma unroll
      for (int sl = 0; sl < 2; ++sl) {
        const int bx = t2*8 + sl*4;
        u32x4 tmp;
        tmp[0] = hi ? Lh[bx+2] : Lh[bx+0];
        tmp[1] = hi ? Lh[bx+3] : Lh[bx+1];
        tmp[2] = hi ? Hh[bx+2] : Hh[bx+0];
        tmp[3] = hi ? Hh[bx+3] : Hh[bx+1];
        bf8 pa = __builtin_bit_cast(bf8, tmp);
        const int sg = t2*2 + sl;
        bf8 v0f = *(const bf8*)(Vc + ((unsigned)((0*32 + l31)*128 + sg*32 + hi*16) ^ swz));
        o0 = __builtin_amdgcn_mfma_f32_32x32x16_bf16(pa, v0f, o0, 0, 0, 0);
        bf8 v1f = *(const bf8*)(Vc + ((unsigned)((1*32 + l31)*128 + sg*32 + hi*16) ^ swz));
        o1 = __builtin_amdgcn_mfma_f32_32x32x16_bf16(pa, v1f, o1, 0, 0, 0);
        o2 = __builtin_amdgcn_mfma_f32_32x32x16_bf16(pa, ones, o2, 0, 0, 0);
      }

    // ---- write next tile of both groups into the other buffer ----
    if (it < 15) {
      const int nxt = cur ^ 1;
      *(bf8*)((char*)KVb[0 + nxt] + kwb) = k0;
      *(bf8*)((char*)KVb[2 + nxt] + kwb) = k1;
      #pragma unroll
      for (int i = 0; i < 8; ++i) {
        unsigned a = (unsigned)((c8 + i) * 128 + sr * 2) ^ ((unsigned)i << 4);
        *(short*)((char*)KVb[4 + nxt] + a) = v0[i];
        *(short*)((char*)KVb[6 + nxt] + a) = v1[i];
      }
      if (t < 64) {
        biasB[0][nxt][t] = mv0 ? (short)0 : (short)0xC680;
        biasB[1][nxt][t] = mv1 ? (short)0 : (short)0xC680;
      }
    }
    __syncthreads();
  }

  // ---- combine: group1 -> LDS, group0 adds (fixed-shift => pure addition) ----
  float* exch = (float*)&KVb[0][0];            // [4 waves][64 lanes][48 f32] = 48 KB
  if (grp == 1) {
    float* p = exch + ((w & 3) * 64 + lane) * 48;
    #pragma unroll
    for (int j = 0; j < 16; ++j) {
      p[j]      = o0[j];
      p[16 + j] = o1[j];
      p[32 + j] = o2[j];
    }
  }
  __syncthreads();
  if (grp == 0) {
    const float* p = exch + ((w & 3) * 64 + lane) * 48;
    #pragma unroll
    for (int j = 0; j < 16; ++j) {
      o0[j] += p[j];
      o1[j] += p[16 + j];
      o2[j] += p[32 + j];
    }
    // ---- normalize, store att[b][l][h*64+d] ----
    #pragma unroll
    for (int r = 0; r < 16; ++r) {
      int qr = (r & 3) + 8 * (r >> 2) + 4 * hi;
      float ls = __shfl(o2[r], hi << 5);     // lsum lives in col-0 lanes (0 and 32)
      float inv = 1.0f / ls;
      long rowb = (long)(b * 2048 + qrow0 + qr) * 1024 + h * 64;
      att[rowb + l31]      = f2bf(o0[r] * inv);
      att[rowb + 32 + l31] = f2bf(o1[r] * inv);
    }
  }
}

extern "C" void kernel_launch(void* const* d_in, const int* in_sizes, int n_in,
                              void* d_out, int out_size, void* d_ws, size_t ws_size,
                              hipStream_t stream) {
  const float* q    = (const float*)d_in[0];
  const float* k    = (const float*)d_in[1];
  const float* v    = (const float*)d_in[2];
  const int*   mask = (const int*)d_in[3];
  const float* w_q  = (const float*)d_in[4];
  const float* w_k  = (const float*)d_in[5];
  const float* w_v  = (const float*)d_in[6];
  const float* w_o  = (const float*)d_in[7];
  float* out = (float*)d_out;

  char* ws = (char*)d_ws;
  const long HSZ = 2L * 16 * 2048 * 64 * sizeof(short);
  short* qh  = (short*)(ws);
  short* kh  = (short*)(ws + HSZ);
  short* vh  = (short*)(ws + 2 * HSZ);
  short* att = (short*)(ws + 3 * HSZ);

  qkv_gemm<<<dim3(32, 8, 3), 256, 0, stream>>>(q, k, v, w_q, w_k, w_v, qh, kh, vh);
  attn_fwd<<<dim3(32, 16), dim3(512), 0, stream>>>(qh, kh, vh, mask, att);
  out_gemm<<<dim3(32, 8), 256, 0, stream>>>(att, w_o, out);
}

// Round 11
// 141.559 us; speedup vs baseline: 1.9152x; 1.9152x over previous
//
#include <hip/hip_runtime.h>
#include <hip/hip_bf16.h>

// MHA block: out = softmax(mask(Q Wq^T (K Wk^T)^T / 8)) (V Wv^T) Wo^T
// B=2, L=2048, D=1024, H=16, Dk=64.
// R11 = attn R9 verbatim (green). GEMMs: all inputs pre-cast to bf16 once
// (cast kernel), then the proven bf16-A staging path for both A and W.

using bf8   = __attribute__((ext_vector_type(8))) short;    // 8 bf16
using f4    = __attribute__((ext_vector_type(4))) float;
using f16v  = __attribute__((ext_vector_type(16))) float;
using u32x4 = __attribute__((ext_vector_type(4))) unsigned int;

__device__ __forceinline__ short f2bf(float f) {
  unsigned u = __float_as_uint(f);
  u = (u + 0x7FFFu + ((u >> 16) & 1u)) >> 16;   // RNE
  return (short)(unsigned short)u;
}

__device__ __forceinline__ unsigned cvt_pk_bf16(float lo, float hi) {
  unsigned r;
  asm("v_cvt_pk_bf16_f32 %0, %1, %2" : "=v"(r) : "v"(lo), "v"(hi));
  return r;
}

// with a=b=x: a' = low-half bcast, b' = high-half bcast
__device__ __forceinline__ void permswap(unsigned &a, unsigned &b) {
  asm volatile("v_permlane32_swap_b32 %0, %1" : "+v"(a), "+v"(b));
}

// ======== one-shot fp32 -> bf16 cast of q,k,v and the 4 weight matrices ========
__global__ __launch_bounds__(256)
void cast_bf16(const float* __restrict__ q, const float* __restrict__ k,
               const float* __restrict__ v, const float* __restrict__ wq,
               const float* __restrict__ wk, const float* __restrict__ wv,
               const float* __restrict__ wo,
               short* __restrict__ qc, short* __restrict__ kc, short* __restrict__ vc,
               short* __restrict__ wqc, short* __restrict__ wkc, short* __restrict__ wvc,
               short* __restrict__ woc)
{
  const int z = blockIdx.z;
  if (z >= 3 && blockIdx.x >= 512) return;     // weights: 1M elems = 512 blocks
  const float* src = (z==0)?q:(z==1)?k:(z==2)?v:(z==3)?wq:(z==4)?wk:(z==5)?wv:wo;
  short* dst       = (z==0)?qc:(z==1)?kc:(z==2)?vc:(z==3)?wqc:(z==4)?wkc:(z==5)?wvc:woc;
  long i = ((long)blockIdx.x * 256 + threadIdx.x) * 8;
  const float4* s4 = (const float4*)(src + i);
  float4 a = s4[0], b = s4[1];
  u32x4 pk;
  pk[0] = cvt_pk_bf16(a.x, a.y);
  pk[1] = cvt_pk_bf16(a.z, a.w);
  pk[2] = cvt_pk_bf16(b.x, b.y);
  pk[3] = cvt_pk_bf16(b.z, b.w);
  *(bf8*)(dst + i) = __builtin_bit_cast(bf8, pk);
}

// ======== GEMM body: R9 structure, both A and W bf16 (proven staging path) ========
// C[m,n] = sum_k A[m,k] * W[n,k]  (x @ W.T); 128x128 tile, BK=32, double-buffered.
template<bool HEADOUT>
__device__ __forceinline__ void gemm_body(const short* __restrict__ Ain,
                                          const short* __restrict__ W,
                                          void* __restrict__ Out,
                                          int bm, int bn, float scale)
{
  constexpr int LDT = 40;                      // 80B rows, 16B aligned
  __shared__ short As[2][128 * LDT];
  __shared__ short Ws[2][128 * LDT];

  const int tid  = threadIdx.x;
  const int lane = tid & 63;
  const int wv   = tid >> 6;
  const int wm = wv >> 1, wn = wv & 1;         // wave tile 64x64
  const int l15 = lane & 15;
  const int lk8 = (lane >> 4) * 8;

  const f4 fz = {0.f, 0.f, 0.f, 0.f};
  f4 acc[4][4];
  #pragma unroll
  for (int mi = 0; mi < 4; ++mi)
    #pragma unroll
    for (int ni = 0; ni < 4; ++ni) acc[mi][ni] = fz;

  const int arow = tid >> 1;                   // 0..127
  const int acol = (tid & 1) * 16;             // 0 / 16

  bf8 ar[2], wr[2];

  auto loadA = [&](int kt) {
    const short* src = Ain + (long)(bm + arow) * 1024 + kt + acol;
    ar[0] = *(const bf8*)src;
    ar[1] = *(const bf8*)(src + 8);
  };
  auto loadW = [&](int kt) {
    const short* src = W + (long)(bn + arow) * 1024 + kt + acol;
    wr[0] = *(const bf8*)src;
    wr[1] = *(const bf8*)(src + 8);
  };
  auto writeTile = [&](int buf) {
    short* ap = &As[buf][arow * LDT + acol];
    *(bf8*)ap     = ar[0];
    *(bf8*)(ap+8) = ar[1];
    short* wp = &Ws[buf][arow * LDT + acol];
    *(bf8*)wp     = wr[0];
    *(bf8*)(wp+8) = wr[1];
  };

  loadA(0); loadW(0); writeTile(0);
  __syncthreads();

  for (int ktI = 0; ktI < 32; ++ktI) {
    const int cur = ktI & 1;
    if (ktI < 31) { loadA((ktI + 1) * 32); loadW((ktI + 1) * 32); }

    bf8 af[4], bfr[4];
    #pragma unroll
    for (int mi = 0; mi < 4; ++mi)
      af[mi] = *(const bf8*)&As[cur][(wm*64 + mi*16 + l15) * LDT + lk8];
    #pragma unroll
    for (int ni = 0; ni < 4; ++ni)
      bfr[ni] = *(const bf8*)&Ws[cur][(wn*64 + ni*16 + l15) * LDT + lk8];
    #pragma unroll
    for (int mi = 0; mi < 4; ++mi)
      #pragma unroll
      for (int ni = 0; ni < 4; ++ni)
        acc[mi][ni] = __builtin_amdgcn_mfma_f32_16x16x32_bf16(af[mi], bfr[ni], acc[mi][ni], 0, 0, 0);

    if (ktI < 31) writeTile(cur ^ 1);
    __syncthreads();
  }

  // epilogue: C/D 16x16 layout: col = lane&15, row = (lane>>4)*4 + r
  #pragma unroll
  for (int mi = 0; mi < 4; ++mi) {
    #pragma unroll
    for (int ni = 0; ni < 4; ++ni) {
      #pragma unroll
      for (int r = 0; r < 4; ++r) {
        int mg = bm + wm*64 + mi*16 + (lane >> 4)*4 + r;
        int ng = bn + wn*64 + ni*16 + l15;
        float val = acc[mi][ni][r] * scale;
        if constexpr (HEADOUT) {
          int b = mg >> 11, l = mg & 2047;
          int h = ng >> 6,  d = ng & 63;
          ((short*)Out)[(((long)(b*16 + h) * 2048 + l) << 6) + d] = f2bf(val);
        } else {
          ((float*)Out)[(long)mg * 1024 + ng] = val;
        }
      }
    }
  }
}

// merged Q/K/V projection: blockIdx.z selects stream -> 768 blocks
__global__ __launch_bounds__(256)
void qkv_gemm(const short* __restrict__ qc, const short* __restrict__ kc,
              const short* __restrict__ vc, const short* __restrict__ wqc,
              const short* __restrict__ wkc, const short* __restrict__ wvc,
              short* __restrict__ qh, short* __restrict__ kh, short* __restrict__ vh)
{
  const int z = blockIdx.z;
  const short* A = (z == 0) ? qc : (z == 1) ? kc : vc;
  const short* W = (z == 0) ? wqc : (z == 1) ? wkc : wvc;
  short* Out     = (z == 0) ? qh : (z == 1) ? kh : vh;
  const float scale = (z == 0) ? 0.125f : 1.0f;
  gemm_body<true>(A, W, Out, blockIdx.x * 128, blockIdx.y * 128, scale);
}

__global__ __launch_bounds__(256)
void out_gemm(const short* __restrict__ att, const short* __restrict__ woc,
              float* __restrict__ out)
{
  gemm_body<false>(att, woc, out, blockIdx.x * 128, blockIdx.y * 128, 1.0f);
}

// ======== flash attention (R9 verbatim, green): 512 thr, KVBLK=128 ========
// grid (32 bh, 8 qtile): same-bh q-blocks at flat stride 32 -> same XCD (L2 K/V reuse).
// Per barrier-iteration: stage 128 keys (dbuf), two 64-key compute halves.
// Swapped QK^T (32x32x16): lane owns q = lane&31; fixed softmax shift m=8;
// masked keys -16384 -> exp2==0. lsum via ones-column MFMA. P via cvt_pk+permlane32.
__global__ __launch_bounds__(512, 2)
void attn_fwd(const short* __restrict__ qh, const short* __restrict__ kh,
              const short* __restrict__ vh, const int* __restrict__ mask,
              short* __restrict__ att)
{
  __shared__ short Kb[2][128 * 64];      // [key][dk], 128B rows, XOR-swizzled
  __shared__ short Vb[2][64 * 128];      // [dk][key], 256B rows, XOR-swizzled
  __shared__ short biasB[2][128];

  const int t = threadIdx.x, lane = t & 63, w = t >> 6;
  const int l31 = lane & 31, hi = lane >> 5;
  const unsigned swz = (unsigned)((l31 & 7) << 4);
  const int bh = blockIdx.x, b = bh >> 4, h = bh & 15;
  const int qrow0 = blockIdx.y * 256 + w * 32;
  const long base = (long)bh * 2048 * 64;

  bf8 qb[4];
  {
    const short* qp = qh + base + (long)(qrow0 + l31) * 64 + hi * 8;
    #pragma unroll
    for (int s = 0; s < 4; ++s) qb[s] = *(const bf8*)(qp + s * 16);
  }
  bf8 qb4;                                   // bias k-step: B[k=0][q] = 1
  #pragma unroll
  for (int i = 0; i < 8; ++i) qb4[i] = 0;
  qb4[0] = hi ? (short)0 : (short)0x3F80;
  bf8 ones;                                  // lsum column: B[k][n=0] = 1
  #pragma unroll
  for (int i = 0; i < 8; ++i) ones[i] = (l31 == 0) ? (short)0x3F80 : (short)0;

  f16v o0, o1, o2, fz16;
  #pragma unroll
  for (int i = 0; i < 16; ++i) { o0[i] = 0.f; o1[i] = 0.f; o2[i] = 0.f; fz16[i] = 0.f; }

  // staging: thread covers K rows {sr, sr+64} chunk c8; V d-rows c8..c8+7, keys {sr, sr+64}
  const int sr = t & 63, c8 = (t >> 6) << 3;
  const short* kgp = kh + base + c8;
  const short* vgp = vh + base + c8;
  const unsigned kwb = (unsigned)(sr * 128 + c8 * 2) ^ ((unsigned)(sr & 7) << 4);

  // prologue: stage tile 0 (keys 0..127) -> buf 0
  {
    bf8 kr  = *(const bf8*)(kgp + (long)sr * 64);
    bf8 kr2 = *(const bf8*)(kgp + (long)(64 + sr) * 64);
    bf8 vr  = *(const bf8*)(vgp + (long)sr * 64);
    bf8 vr2 = *(const bf8*)(vgp + (long)(64 + sr) * 64);
    *(bf8*)((char*)Kb[0] + kwb)        = kr;
    *(bf8*)((char*)Kb[0] + kwb + 8192) = kr2;     // key row sr+64; (sr+64)&7 == sr&7
    #pragma unroll
    for (int i = 0; i < 8; ++i) {
      unsigned a0 = (unsigned)((c8 + i) * 256 + sr * 2)        ^ ((unsigned)(i & 7) << 4);
      unsigned a1 = (unsigned)((c8 + i) * 256 + (64 + sr) * 2) ^ ((unsigned)(i & 7) << 4);
      *(short*)((char*)Vb[0] + a0) = vr[i];
      *(short*)((char*)Vb[0] + a1) = vr2[i];
    }
    if (t < 128) biasB[0][t] = mask[b * 2048 + t] ? (short)0 : (short)0xC680; // bf16(-16384)
  }
  __syncthreads();

  for (int it = 0; it < 16; ++it) {
    const int cur = it & 1;
    bf8 kr, kr2, vr, vr2; int mv = 1;
    if (it < 15) {                           // issue next-tile loads early (T14)
      const int kt = (it + 1) * 128;
      kr  = *(const bf8*)(kgp + (long)(kt + sr) * 64);
      kr2 = *(const bf8*)(kgp + (long)(kt + 64 + sr) * 64);
      vr  = *(const bf8*)(vgp + (long)(kt + sr) * 64);
      vr2 = *(const bf8*)(vgp + (long)(kt + 64 + sr) * 64);
      if (t < 128) mv = mask[b * 2048 + kt + t];
    }

    const char* Kc = (const char*)Kb[cur];
    const char* Vc = (const char*)Vb[cur];

    #pragma unroll
    for (int ha = 0; ha < 2; ++ha) {         // two 64-key halves per barrier
      const int ko = ha * 64;

      // ---- S^T = mfma(K, Q) + bias column ----
      f16v sT[2];
      #pragma unroll
      for (int kb2 = 0; kb2 < 2; ++kb2) {
        bf8 ba;
        #pragma unroll
        for (int i = 0; i < 8; ++i) ba[i] = 0;
        ba[0] = hi ? (short)0 : biasB[cur][ko + kb2 * 32 + l31];
        sT[kb2] = __builtin_amdgcn_mfma_f32_32x32x16_bf16(ba, qb4, fz16, 0, 0, 0);
        #pragma unroll
        for (int s = 0; s < 4; ++s) {
          unsigned ab = (unsigned)((ko + kb2 * 32 + l31) * 128 + s * 32 + hi * 16) ^ swz;
          bf8 ka = *(const bf8*)(Kc + ab);
          sT[kb2] = __builtin_amdgcn_mfma_f32_32x32x16_bf16(ka, qb[s], sT[kb2], 0, 0, 0);
        }
      }

      // ---- p = exp2(s*log2e - 8*log2e); pack bf16 pairs; swap halves ----
      unsigned Lh[16], Hh[16];
      #pragma unroll
      for (int t2 = 0; t2 < 2; ++t2)
        #pragma unroll
        for (int pi = 0; pi < 8; ++pi) {
          float pe0 = exp2f(sT[t2][2*pi]   * 1.44269504f - 11.5415603f);
          float pe1 = exp2f(sT[t2][2*pi+1] * 1.44269504f - 11.5415603f);
          unsigned pkv = cvt_pk_bf16(pe0, pe1);
          unsigned Lv = pkv, Hv = pkv;
          permswap(Lv, Hv);
          Lh[t2*8 + pi] = Lv; Hh[t2*8 + pi] = Hv;
        }

      // ---- O += P V ; lsum += P 1 ----
      #pragma unroll
      for (int t2 = 0; t2 < 2; ++t2)
        #pragma unroll
        for (int sl = 0; sl < 2; ++sl) {
          const int bx = t2*8 + sl*4;
          u32x4 tmp;
          tmp[0] = hi ? Lh[bx+2] : Lh[bx+0];
          tmp[1] = hi ? Lh[bx+3] : Lh[bx+1];
          tmp[2] = hi ? Hh[bx+2] : Hh[bx+0];
          tmp[3] = hi ? Hh[bx+3] : Hh[bx+1];
          bf8 pa = __builtin_bit_cast(bf8, tmp);
          const int sg = t2*2 + sl;
          bf8 v0f = *(const bf8*)(Vc + ((unsigned)((0*32 + l31)*256 + ko*2 + sg*32 + hi*16) ^ swz));
          o0 = __builtin_amdgcn_mfma_f32_32x32x16_bf16(pa, v0f, o0, 0, 0, 0);
          bf8 v1f = *(const bf8*)(Vc + ((unsigned)((1*32 + l31)*256 + ko*2 + sg*32 + hi*16) ^ swz));
          o1 = __builtin_amdgcn_mfma_f32_32x32x16_bf16(pa, v1f, o1, 0, 0, 0);
          o2 = __builtin_amdgcn_mfma_f32_32x32x16_bf16(pa, ones, o2, 0, 0, 0);
        }
    }

    // ---- write next tile into the other buffer ----
    if (it < 15) {
      const int nxt = cur ^ 1;
      *(bf8*)((char*)Kb[nxt] + kwb)        = kr;
      *(bf8*)((char*)Kb[nxt] + kwb + 8192) = kr2;
      #pragma unroll
      for (int i = 0; i < 8; ++i) {
        unsigned a0 = (unsigned)((c8 + i) * 256 + sr * 2)        ^ ((unsigned)(i & 7) << 4);
        unsigned a1 = (unsigned)((c8 + i) * 256 + (64 + sr) * 2) ^ ((unsigned)(i & 7) << 4);
        *(short*)((char*)Vb[nxt] + a0) = vr[i];
        *(short*)((char*)Vb[nxt] + a1) = vr2[i];
      }
      if (t < 128) biasB[nxt][t] = mv ? (short)0 : (short)0xC680;
    }
    __syncthreads();
  }

  // ---- epilogue: normalize, store att[b][l][h*64+d] ----
  #pragma unroll
  for (int r = 0; r < 16; ++r) {
    int qr = (r & 3) + 8 * (r >> 2) + 4 * hi;
    float ls = __shfl(o2[r], hi << 5);       // lsum lives in col-0 lanes (0 and 32)
    float inv = 1.0f / ls;
    long rowb = (long)(b * 2048 + qrow0 + qr) * 1024 + h * 64;
    att[rowb + l31]      = f2bf(o0[r] * inv);
    att[rowb + 32 + l31] = f2bf(o1[r] * inv);
  }
}

extern "C" void kernel_launch(void* const* d_in, const int* in_sizes, int n_in,
                              void* d_out, int out_size, void* d_ws, size_t ws_size,
                              hipStream_t stream) {
  const float* q    = (const float*)d_in[0];
  const float* k    = (const float*)d_in[1];
  const float* v    = (const float*)d_in[2];
  const int*   mask = (const int*)d_in[3];
  const float* w_q  = (const float*)d_in[4];
  const float* w_k  = (const float*)d_in[5];
  const float* w_v  = (const float*)d_in[6];
  const float* w_o  = (const float*)d_in[7];
  float* out = (float*)d_out;

  char* ws = (char*)d_ws;
  const long HSZ = 2L * 16 * 2048 * 64 * sizeof(short);   // 8 MB
  const long WSZ = 1024L * 1024 * sizeof(short);          // 2 MB
  short* qh  = (short*)(ws);
  short* kh  = (short*)(ws + HSZ);
  short* vh  = (short*)(ws + 2 * HSZ);
  short* att = (short*)(ws + 3 * HSZ);
  short* qc  = (short*)(ws + 4 * HSZ);
  short* kc  = (short*)(ws + 5 * HSZ);
  short* vc  = (short*)(ws + 6 * HSZ);
  short* wqc = (short*)(ws + 7 * HSZ);
  short* wkc = (short*)(ws + 7 * HSZ + WSZ);
  short* wvc = (short*)(ws + 7 * HSZ + 2 * WSZ);
  short* woc = (short*)(ws + 7 * HSZ + 3 * WSZ);

  cast_bf16<<<dim3(2048, 1, 7), 256, 0, stream>>>(q, k, v, w_q, w_k, w_v, w_o,
                                                  qc, kc, vc, wqc, wkc, wvc, woc);
  qkv_gemm<<<dim3(32, 8, 3), 256, 0, stream>>>(qc, kc, vc, wqc, wkc, wvc, qh, kh, vh);
  attn_fwd<<<dim3(32, 8), dim3(512), 0, stream>>>(qh, kh, vh, mask, att);
  out_gemm<<<dim3(32, 8), 256, 0, stream>>>(att, woc, out);
}

// Round 14
// 139.573 us; speedup vs baseline: 1.9424x; 1.0142x over previous
//
#include <hip/hip_runtime.h>
#include <hip/hip_bf16.h>

// MHA block: out = softmax(mask(Q Wq^T (K Wk^T)^T / 8)) (V Wv^T) Wo^T
// B=2, L=2048, D=1024, H=16, Dk=64.
// R14 = R11 (green) + ONLY the constant folding: Q-scale 0.125*log2e, bias
// column -11.5625 (unmasked, uniform -> cancels) / -16384 (masked -> p=0),
// exp via the R11-proven exp2f() on the pre-folded argument.
// NO setprio, NO inline-asm/builtin exp (isolating R12/R13's failure).

using bf8   = __attribute__((ext_vector_type(8))) short;    // 8 bf16
using f4    = __attribute__((ext_vector_type(4))) float;
using f16v  = __attribute__((ext_vector_type(16))) float;
using u32x4 = __attribute__((ext_vector_type(4))) unsigned int;

__device__ __forceinline__ short f2bf(float f) {
  unsigned u = __float_as_uint(f);
  u = (u + 0x7FFFu + ((u >> 16) & 1u)) >> 16;   // RNE
  return (short)(unsigned short)u;
}

__device__ __forceinline__ unsigned cvt_pk_bf16(float lo, float hi) {
  unsigned r;
  asm("v_cvt_pk_bf16_f32 %0, %1, %2" : "=v"(r) : "v"(lo), "v"(hi));
  return r;
}

// with a=b=x: a' = low-half bcast, b' = high-half bcast
__device__ __forceinline__ void permswap(unsigned &a, unsigned &b) {
  asm volatile("v_permlane32_swap_b32 %0, %1" : "+v"(a), "+v"(b));
}

// ======== one-shot fp32 -> bf16 cast of q,k,v and the 4 weight matrices ========
__global__ __launch_bounds__(256)
void cast_bf16(const float* __restrict__ q, const float* __restrict__ k,
               const float* __restrict__ v, const float* __restrict__ wq,
               const float* __restrict__ wk, const float* __restrict__ wv,
               const float* __restrict__ wo,
               short* __restrict__ qc, short* __restrict__ kc, short* __restrict__ vc,
               short* __restrict__ wqc, short* __restrict__ wkc, short* __restrict__ wvc,
               short* __restrict__ woc)
{
  const int z = blockIdx.z;
  if (z >= 3 && blockIdx.x >= 512) return;     // weights: 1M elems = 512 blocks
  const float* src = (z==0)?q:(z==1)?k:(z==2)?v:(z==3)?wq:(z==4)?wk:(z==5)?wv:wo;
  short* dst       = (z==0)?qc:(z==1)?kc:(z==2)?vc:(z==3)?wqc:(z==4)?wkc:(z==5)?wvc:woc;
  long i = ((long)blockIdx.x * 256 + threadIdx.x) * 8;
  const float4* s4 = (const float4*)(src + i);
  float4 a = s4[0], b = s4[1];
  u32x4 pk;
  pk[0] = cvt_pk_bf16(a.x, a.y);
  pk[1] = cvt_pk_bf16(a.z, a.w);
  pk[2] = cvt_pk_bf16(b.x, b.y);
  pk[3] = cvt_pk_bf16(b.z, b.w);
  *(bf8*)(dst + i) = __builtin_bit_cast(bf8, pk);
}

// ======== GEMM body (R11 verbatim): 128x128 tile, BK=32, bf16 A and W ========
template<bool HEADOUT>
__device__ __forceinline__ void gemm_body(const short* __restrict__ Ain,
                                          const short* __restrict__ W,
                                          void* __restrict__ Out,
                                          int bm, int bn, float scale)
{
  constexpr int LDT = 40;                      // 80B rows, 16B aligned
  __shared__ short As[2][128 * LDT];
  __shared__ short Ws[2][128 * LDT];

  const int tid  = threadIdx.x;
  const int lane = tid & 63;
  const int wv   = tid >> 6;
  const int wm = wv >> 1, wn = wv & 1;         // wave tile 64x64
  const int l15 = lane & 15;
  const int lk8 = (lane >> 4) * 8;

  const f4 fz = {0.f, 0.f, 0.f, 0.f};
  f4 acc[4][4];
  #pragma unroll
  for (int mi = 0; mi < 4; ++mi)
    #pragma unroll
    for (int ni = 0; ni < 4; ++ni) acc[mi][ni] = fz;

  const int arow = tid >> 1;                   // 0..127
  const int acol = (tid & 1) * 16;             // 0 / 16

  bf8 ar[2], wr[2];

  auto loadA = [&](int kt) {
    const short* src = Ain + (long)(bm + arow) * 1024 + kt + acol;
    ar[0] = *(const bf8*)src;
    ar[1] = *(const bf8*)(src + 8);
  };
  auto loadW = [&](int kt) {
    const short* src = W + (long)(bn + arow) * 1024 + kt + acol;
    wr[0] = *(const bf8*)src;
    wr[1] = *(const bf8*)(src + 8);
  };
  auto writeTile = [&](int buf) {
    short* ap = &As[buf][arow * LDT + acol];
    *(bf8*)ap     = ar[0];
    *(bf8*)(ap+8) = ar[1];
    short* wp = &Ws[buf][arow * LDT + acol];
    *(bf8*)wp     = wr[0];
    *(bf8*)(wp+8) = wr[1];
  };

  loadA(0); loadW(0); writeTile(0);
  __syncthreads();

  for (int ktI = 0; ktI < 32; ++ktI) {
    const int cur = ktI & 1;
    if (ktI < 31) { loadA((ktI + 1) * 32); loadW((ktI + 1) * 32); }

    bf8 af[4], bfr[4];
    #pragma unroll
    for (int mi = 0; mi < 4; ++mi)
      af[mi] = *(const bf8*)&As[cur][(wm*64 + mi*16 + l15) * LDT + lk8];
    #pragma unroll
    for (int ni = 0; ni < 4; ++ni)
      bfr[ni] = *(const bf8*)&Ws[cur][(wn*64 + ni*16 + l15) * LDT + lk8];
    #pragma unroll
    for (int mi = 0; mi < 4; ++mi)
      #pragma unroll
      for (int ni = 0; ni < 4; ++ni)
        acc[mi][ni] = __builtin_amdgcn_mfma_f32_16x16x32_bf16(af[mi], bfr[ni], acc[mi][ni], 0, 0, 0);

    if (ktI < 31) writeTile(cur ^ 1);
    __syncthreads();
  }

  // epilogue: C/D 16x16 layout: col = lane&15, row = (lane>>4)*4 + r
  #pragma unroll
  for (int mi = 0; mi < 4; ++mi) {
    #pragma unroll
    for (int ni = 0; ni < 4; ++ni) {
      #pragma unroll
      for (int r = 0; r < 4; ++r) {
        int mg = bm + wm*64 + mi*16 + (lane >> 4)*4 + r;
        int ng = bn + wn*64 + ni*16 + l15;
        float val = acc[mi][ni][r] * scale;
        if constexpr (HEADOUT) {
          int b = mg >> 11, l = mg & 2047;
          int h = ng >> 6,  d = ng & 63;
          ((short*)Out)[(((long)(b*16 + h) * 2048 + l) << 6) + d] = f2bf(val);
        } else {
          ((float*)Out)[(long)mg * 1024 + ng] = val;
        }
      }
    }
  }
}

// merged Q/K/V projection: blockIdx.z selects stream -> 768 blocks
// Q scale folds softmax's log2e: 0.125 * 1.44269504
__global__ __launch_bounds__(256)
void qkv_gemm(const short* __restrict__ qc, const short* __restrict__ kc,
              const short* __restrict__ vc, const short* __restrict__ wqc,
              const short* __restrict__ wkc, const short* __restrict__ wvc,
              short* __restrict__ qh, short* __restrict__ kh, short* __restrict__ vh)
{
  const int z = blockIdx.z;
  const short* A = (z == 0) ? qc : (z == 1) ? kc : vc;
  const short* W = (z == 0) ? wqc : (z == 1) ? wkc : wvc;
  short* Out     = (z == 0) ? qh : (z == 1) ? kh : vh;
  const float scale = (z == 0) ? 0.18033688f : 1.0f;
  gemm_body<true>(A, W, Out, blockIdx.x * 128, blockIdx.y * 128, scale);
}

__global__ __launch_bounds__(256)
void out_gemm(const short* __restrict__ att, const short* __restrict__ woc,
              float* __restrict__ out)
{
  gemm_body<false>(att, woc, out, blockIdx.x * 128, blockIdx.y * 128, 1.0f);
}

// ======== flash attention (R9 structure): 512 thr, KVBLK=128 ========
// Scores arrive as s*log2e (scale folded in Q); bias column adds -11.5625
// (unmasked; uniform shift, cancels in normalization) or -16384 (masked -> p=0).
// p = exp2f(sT) (R11-proven path, pre-folded argument). No setprio.
__global__ __launch_bounds__(512, 2)
void attn_fwd(const short* __restrict__ qh, const short* __restrict__ kh,
              const short* __restrict__ vh, const int* __restrict__ mask,
              short* __restrict__ att)
{
  __shared__ short Kb[2][128 * 64];      // [key][dk], 128B rows, XOR-swizzled
  __shared__ short Vb[2][64 * 128];      // [dk][key], 256B rows, XOR-swizzled
  __shared__ short biasB[2][128];

  const int t = threadIdx.x, lane = t & 63, w = t >> 6;
  const int l31 = lane & 31, hi = lane >> 5;
  const unsigned swz = (unsigned)((l31 & 7) << 4);
  const int bh = blockIdx.x, b = bh >> 4, h = bh & 15;
  const int qrow0 = blockIdx.y * 256 + w * 32;
  const long base = (long)bh * 2048 * 64;

  bf8 qb[4];
  {
    const short* qp = qh + base + (long)(qrow0 + l31) * 64 + hi * 8;
    #pragma unroll
    for (int s = 0; s < 4; ++s) qb[s] = *(const bf8*)(qp + s * 16);
  }
  bf8 qb4;                                   // bias k-step: B[k=0][q] = 1
  #pragma unroll
  for (int i = 0; i < 8; ++i) qb4[i] = 0;
  qb4[0] = hi ? (short)0 : (short)0x3F80;
  bf8 ones;                                  // lsum column: B[k][n=0] = 1
  #pragma unroll
  for (int i = 0; i < 8; ++i) ones[i] = (l31 == 0) ? (short)0x3F80 : (short)0;

  f16v o0, o1, o2, fz16;
  #pragma unroll
  for (int i = 0; i < 16; ++i) { o0[i] = 0.f; o1[i] = 0.f; o2[i] = 0.f; fz16[i] = 0.f; }

  // staging: thread covers K rows {sr, sr+64} chunk c8; V d-rows c8..c8+7, keys {sr, sr+64}
  const int sr = t & 63, c8 = (t >> 6) << 3;
  const short* kgp = kh + base + c8;
  const short* vgp = vh + base + c8;
  const unsigned kwb = (unsigned)(sr * 128 + c8 * 2) ^ ((unsigned)(sr & 7) << 4);

  // bias: unmasked = bf16(-11.5625) = 0xC139 (uniform shift, cancels in norm);
  // masked = bf16(-16384) = 0xC680 -> 2^x == 0.
  // prologue: stage tile 0 (keys 0..127) -> buf 0
  {
    bf8 kr  = *(const bf8*)(kgp + (long)sr * 64);
    bf8 kr2 = *(const bf8*)(kgp + (long)(64 + sr) * 64);
    bf8 vr  = *(const bf8*)(vgp + (long)sr * 64);
    bf8 vr2 = *(const bf8*)(vgp + (long)(64 + sr) * 64);
    *(bf8*)((char*)Kb[0] + kwb)        = kr;
    *(bf8*)((char*)Kb[0] + kwb + 8192) = kr2;     // key row sr+64; (sr+64)&7 == sr&7
    #pragma unroll
    for (int i = 0; i < 8; ++i) {
      unsigned a0 = (unsigned)((c8 + i) * 256 + sr * 2)        ^ ((unsigned)(i & 7) << 4);
      unsigned a1 = (unsigned)((c8 + i) * 256 + (64 + sr) * 2) ^ ((unsigned)(i & 7) << 4);
      *(short*)((char*)Vb[0] + a0) = vr[i];
      *(short*)((char*)Vb[0] + a1) = vr2[i];
    }
    if (t < 128) biasB[0][t] = mask[b * 2048 + t] ? (short)0xC139 : (short)0xC680;
  }
  __syncthreads();

  for (int it = 0; it < 16; ++it) {
    const int cur = it & 1;
    bf8 kr, kr2, vr, vr2; int mv = 1;
    if (it < 15) {                           // issue next-tile loads early (T14)
      const int kt = (it + 1) * 128;
      kr  = *(const bf8*)(kgp + (long)(kt + sr) * 64);
      kr2 = *(const bf8*)(kgp + (long)(kt + 64 + sr) * 64);
      vr  = *(const bf8*)(vgp + (long)(kt + sr) * 64);
      vr2 = *(const bf8*)(vgp + (long)(kt + 64 + sr) * 64);
      if (t < 128) mv = mask[b * 2048 + kt + t];
    }

    const char* Kc = (const char*)Kb[cur];
    const char* Vc = (const char*)Vb[cur];

    #pragma unroll
    for (int ha = 0; ha < 2; ++ha) {         // two 64-key halves per barrier
      const int ko = ha * 64;

      // ---- S^T = mfma(K, Q) + bias column ----
      f16v sT[2];
      #pragma unroll
      for (int kb2 = 0; kb2 < 2; ++kb2) {
        bf8 ba;
        #pragma unroll
        for (int i = 0; i < 8; ++i) ba[i] = 0;
        ba[0] = hi ? (short)0 : biasB[cur][ko + kb2 * 32 + l31];
        sT[kb2] = __builtin_amdgcn_mfma_f32_32x32x16_bf16(ba, qb4, fz16, 0, 0, 0);
        #pragma unroll
        for (int s = 0; s < 4; ++s) {
          unsigned ab = (unsigned)((ko + kb2 * 32 + l31) * 128 + s * 32 + hi * 16) ^ swz;
          bf8 ka = *(const bf8*)(Kc + ab);
          sT[kb2] = __builtin_amdgcn_mfma_f32_32x32x16_bf16(ka, qb[s], sT[kb2], 0, 0, 0);
        }
      }

      // ---- p = 2^sT (scale+shift folded); pack bf16; swap halves ----
      unsigned Lh[16], Hh[16];
      #pragma unroll
      for (int t2 = 0; t2 < 2; ++t2)
        #pragma unroll
        for (int pi = 0; pi < 8; ++pi) {
          float pe0 = exp2f(sT[t2][2*pi]);
          float pe1 = exp2f(sT[t2][2*pi+1]);
          unsigned pkv = cvt_pk_bf16(pe0, pe1);
          unsigned Lv = pkv, Hv = pkv;
          permswap(Lv, Hv);
          Lh[t2*8 + pi] = Lv; Hh[t2*8 + pi] = Hv;
        }

      // ---- O += P V ; lsum += P 1 ----
      #pragma unroll
      for (int t2 = 0; t2 < 2; ++t2)
        #pragma unroll
        for (int sl = 0; sl < 2; ++sl) {
          const int bx = t2*8 + sl*4;
          u32x4 tmp;
          tmp[0] = hi ? Lh[bx+2] : Lh[bx+0];
          tmp[1] = hi ? Lh[bx+3] : Lh[bx+1];
          tmp[2] = hi ? Hh[bx+2] : Hh[bx+0];
          tmp[3] = hi ? Hh[bx+3] : Hh[bx+1];
          bf8 pa = __builtin_bit_cast(bf8, tmp);
          const int sg = t2*2 + sl;
          bf8 v0f = *(const bf8*)(Vc + ((unsigned)((0*32 + l31)*256 + ko*2 + sg*32 + hi*16) ^ swz));
          o0 = __builtin_amdgcn_mfma_f32_32x32x16_bf16(pa, v0f, o0, 0, 0, 0);
          bf8 v1f = *(const bf8*)(Vc + ((unsigned)((1*32 + l31)*256 + ko*2 + sg*32 + hi*16) ^ swz));
          o1 = __builtin_amdgcn_mfma_f32_32x32x16_bf16(pa, v1f, o1, 0, 0, 0);
          o2 = __builtin_amdgcn_mfma_f32_32x32x16_bf16(pa, ones, o2, 0, 0, 0);
        }
    }

    // ---- write next tile into the other buffer ----
    if (it < 15) {
      const int nxt = cur ^ 1;
      *(bf8*)((char*)Kb[nxt] + kwb)        = kr;
      *(bf8*)((char*)Kb[nxt] + kwb + 8192) = kr2;
      #pragma unroll
      for (int i = 0; i < 8; ++i) {
        unsigned a0 = (unsigned)((c8 + i) * 256 + sr * 2)        ^ ((unsigned)(i & 7) << 4);
        unsigned a1 = (unsigned)((c8 + i) * 256 + (64 + sr) * 2) ^ ((unsigned)(i & 7) << 4);
        *(short*)((char*)Vb[nxt] + a0) = vr[i];
        *(short*)((char*)Vb[nxt] + a1) = vr2[i];
      }
      if (t < 128) biasB[nxt][t] = mv ? (short)0xC139 : (short)0xC680;
    }
    __syncthreads();
  }

  // ---- epilogue: normalize, store att[b][l][h*64+d] ----
  #pragma unroll
  for (int r = 0; r < 16; ++r) {
    int qr = (r & 3) + 8 * (r >> 2) + 4 * hi;
    float ls = __shfl(o2[r], hi << 5);       // lsum lives in col-0 lanes (0 and 32)
    float inv = 1.0f / ls;
    long rowb = (long)(b * 2048 + qrow0 + qr) * 1024 + h * 64;
    att[rowb + l31]      = f2bf(o0[r] * inv);
    att[rowb + 32 + l31] = f2bf(o1[r] * inv);
  }
}

extern "C" void kernel_launch(void* const* d_in, const int* in_sizes, int n_in,
                              void* d_out, int out_size, void* d_ws, size_t ws_size,
                              hipStream_t stream) {
  const float* q    = (const float*)d_in[0];
  const float* k    = (const float*)d_in[1];
  const float* v    = (const float*)d_in[2];
  const int*   mask = (const int*)d_in[3];
  const float* w_q  = (const float*)d_in[4];
  const float* w_k  = (const float*)d_in[5];
  const float* w_v  = (const float*)d_in[6];
  const float* w_o  = (const float*)d_in[7];
  float* out = (float*)d_out;

  char* ws = (char*)d_ws;
  const long HSZ = 2L * 16 * 2048 * 64 * sizeof(short);   // 8 MB
  const long WSZ = 1024L * 1024 * sizeof(short);          // 2 MB
  short* qh  = (short*)(ws);
  short* kh  = (short*)(ws + HSZ);
  short* vh  = (short*)(ws + 2 * HSZ);
  short* att = (short*)(ws + 3 * HSZ);
  short* qc  = (short*)(ws + 4 * HSZ);
  short* kc  = (short*)(ws + 5 * HSZ);
  short* vc  = (short*)(ws + 6 * HSZ);
  short* wqc = (short*)(ws + 7 * HSZ);
  short* wkc = (short*)(ws + 7 * HSZ + WSZ);
  short* wvc = (short*)(ws + 7 * HSZ + 2 * WSZ);
  short* woc = (short*)(ws + 7 * HSZ + 3 * WSZ);

  cast_bf16<<<dim3(2048, 1, 7), 256, 0, stream>>>(q, k, v, w_q, w_k, w_v, w_o,
                                                  qc, kc, vc, wqc, wkc, wvc, woc);
  qkv_gemm<<<dim3(32, 8, 3), 256, 0, stream>>>(qc, kc, vc, wqc, wkc, wvc, qh, kh, vh);
  attn_fwd<<<dim3(32, 8), dim3(512), 0, stream>>>(qh, kh, vh, mask, att);
  out_gemm<<<dim3(32, 8), 256, 0, stream>>>(att, woc, out);
}